// Round 14
// baseline (151.115 us; speedup 1.0000x reference)
//
#include <hip/hip_runtime.h>
#include <math.h>

#define NQ 12
#define NL 4
#define NA 6
#define BATCH 4096
#define NT 256
#define RSTR 17   // b32 row stride (dwords): stride-17 dword access = 2 lanes/bank (free, m136)

typedef float f2 __attribute__((ext_vector_type(2)));
typedef __fp16 h2 __attribute__((ext_vector_type(2)));   // R13 fix: builtin returns __fp16 vec, not _Float16

// HW-verified (R3-R12) packed complex primitives; (re,im) in a VGPR pair.
#define CMUL(d, u, a)  asm("v_pk_mul_f32 %0, %1, %2 op_sel_hi:[0,1]"                 : "=v"(d) : "v"(u), "v"(a))
#define CMACR(d, u, a) asm("v_pk_fma_f32 %0, %1, %2, %0 op_sel_hi:[0,1,1]"           : "+v"(d) : "v"(u), "v"(a))
#define CMACI(d, u, a) asm("v_pk_fma_f32 %0, %1, %2, %0 op_sel:[1,1,0] op_sel_hi:[1,0,1] neg_lo:[1,0,0]" : "+v"(d) : "v"(u), "v"(a))
#define RYMULS(d, u, a)  asm("v_pk_mul_f32 %0, %1, %2 op_sel:[1,0] op_sel_hi:[1,1]"  : "=v"(d) : "v"(u), "v"(a))
#define RYMACNS(d, u, a) asm("v_pk_fma_f32 %0, %1, %2, %0 op_sel:[1,0,0] op_sel_hi:[1,1,1] neg_lo:[1,0,0] neg_hi:[1,0,0]" : "+v"(d) : "v"(u), "v"(a))
#define WFENCE() asm volatile("s_waitcnt lgkmcnt(0)" ::: "memory")

// f2 <-> packed f16x2 in one f32 slot (v_cvt_pkrtz_f16_f32 is single-inst)
#define PACKH(v)   ({ union { h2 h; float f; } _u; _u.h = __builtin_amdgcn_cvt_pkrtz((v).x, (v).y); _u.f; })
#define UNPACKH(fv) ({ union { h2 h; float f; } _u; _u.f = (fv); (f2){ (float)_u.h.x, (float)_u.h.y }; })

// Real RY butterfly: n0 = c*a0 - s*a1 ; n1 = s*a0 + c*a1   (4 pk ops)
#define RYBFLY(A0, A1, CS) do { \
    f2 _a0 = (A0), _a1 = (A1), _n0, _n1; \
    CMUL  (_n0, CS, _a0); RYMACNS(_n0, CS, _a1); \
    RYMULS(_n1, CS, _a0); CMACR  (_n1, CS, _a1); \
    (A0) = _n0; (A1) = _n1; } while (0)

#define RYGATE(gidx, bq) do { \
    const f2 cs = *(const f2*)(rots + (gidx) * 2); \
    const int S = 1 << (bq); \
    _Pragma("unroll") \
    for (int m = 0; m < 8; ++m) { \
        const int j0 = ((m & ~(S - 1)) << 1) | (m & (S - 1)); \
        RYBFLY(st[j0], st[j0 + S], cs); \
    } } while (0)

// Circuit algebra (R10-verified): Rot = RZ(omega)*RY(theta)*RZ(phi); diagonals folded.
// Layouts + T_a/T_b formulas + CZ parities: R8/R11-verified, verbatim.
// R13/R14: transposes carry state as packed f16x2 per amp (1 b32/amp): R11's DS-inst count at
// R10's LDS footprint; stride-17 dword pattern is conflict-free (2 lanes/bank).
// d_ws: [0..95] 48 gates (c,s) | [96..143] alphas[4][12] | [144..271] dreg[4][16] (re,im)

__global__ void setup_kernel(const float* __restrict__ weights, float* __restrict__ ws) {
    const int t = threadIdx.x;   // 64 threads
    if (t < NL * NQ) {
        const float th = weights[t * 3 + 1];
        float s, c;
        sincosf(0.5f * th, &s, &c);
        ws[t * 2 + 0] = c; ws[t * 2 + 1] = s;
        const int r = t / NQ, q = t % NQ;
        float a;
        if (r == 0) a = 0.5f * weights[q * 3 + 0];
        else        a = 0.5f * (weights[((r - 1) * NQ + q) * 3 + 2] +
                                 weights[(r * NQ + q) * 3 + 0]);
        ws[96 + t] = a;
    }
    {
        const int d = t >> 4, j = t & 15;
        int wq[4];
        if (d == 1 || d == 3) { wq[0] = 0; wq[1] = 1; wq[2] = 6; wq[3] = 7; }
        else                  { wq[0] = 8; wq[1] = 9; wq[2] = 10; wq[3] = 11; }
        float g = 0.0f;
#pragma unroll
        for (int k = 0; k < 4; ++k) {
            const int q = wq[k];
            const float a = (d == 0) ? 0.5f * weights[q * 3 + 0]
                                     : 0.5f * (weights[((d - 1) * NQ + q) * 3 + 2] +
                                               weights[(d * NQ + q) * 3 + 0]);
            g += ((j >> (3 - k)) & 1) ? a : -a;
        }
        float sg, cg;
        sincosf(g, &sg, &cg);
        ws[144 + (d * 16 + j) * 2 + 0] = cg;
        ws[144 + (d * 16 + j) * 2 + 1] = sg;
    }
}

// st[j] *= (cos b, sin b) * dreg_tab[j]   (R10-verified)
__device__ __forceinline__ void apply_phase(f2* st, const float* tab, float beta) {
    float sb, cb;
    sincosf(beta, &sb, &cb);
    const f2 Dth = (f2){cb, sb};
#pragma unroll
    for (int j = 0; j < 16; ++j) {
        const f2 a = st[j];
        f2 t, u;
        CMUL(t, Dth, a); CMACI(t, Dth, a);
        const f2 dg = *(const f2*)(tab + 2 * j);
        CMUL(u, dg, t); CMACI(u, dg, t);
        st[j] = u;
    }
}

__global__ __launch_bounds__(NT) void qdqn_kernel(
    const float* __restrict__ x,       // [BATCH,12]
    const float* __restrict__ rots,    // d_ws tables
    const float* __restrict__ fc_w,    // [6,12]
    const float* __restrict__ fc_b,    // [6]
    float* __restrict__ out)           // [BATCH,6]
{
    __shared__ __align__(16) float buf[NT * RSTR];   // 17408 B packed-f16 transpose buffer
    __shared__ float encc[NQ], encs[NQ];
    __shared__ float red[4][NQ];
    __shared__ float qout[NQ];

    const int tix = threadIdx.x;
    const int lam = tix & 63;
    const int w   = tix >> 6;
    const int w1  = (w >> 1) & 1, w0 = w & 1;
    const int b   = blockIdx.x;

    const float* alph = rots + 96;
    const float* dreg = rots + 144;

    if (tix < NQ) {
        float s, c;
        sincosf(0.5f * x[b * NQ + tix], &s, &c);
        encc[tix] = c; encs[tix] = s;
    }
    __syncthreads();

    // --- RY product state in L1 (real) ---
    f2 st[16];
    {
        float pre = 1.0f;
#pragma unroll
        for (int q = 0; q < 6; ++q)
            pre *= ((lam >> (5 - q)) & 1) ? encs[q] : encc[q];
        pre *= w1 ? encs[6] : encc[6];
        pre *= w0 ? encs[7] : encc[7];
        const float c8 = encc[8],  s8 = encs[8];
        const float c9 = encc[9],  s9 = encs[9];
        const float cA = encc[10], sA = encs[10];
        const float cB = encc[11], sB = encs[11];
#pragma unroll
        for (int j = 0; j < 16; ++j) {
            float v = pre;
            v *= (j & 8) ? s8 : c8;
            v *= (j & 4) ? s9 : c9;
            v *= (j & 2) ? sA : cA;
            v *= (j & 1) ? sB : cB;
            st[j] = (f2){ v, 0.0f };
        }
    }

#define BETA_L1(al) ( (((lam >> 5) & 1) ? (al)[0] : -(al)[0]) + (((lam >> 4) & 1) ? (al)[1] : -(al)[1]) \
                    + (((lam >> 3) & 1) ? (al)[2] : -(al)[2]) + (((lam >> 2) & 1) ? (al)[3] : -(al)[3]) \
                    + (((lam >> 1) & 1) ? (al)[4] : -(al)[4]) + (((lam >> 0) & 1) ? (al)[5] : -(al)[5]) \
                    + (w1 ? (al)[6] : -(al)[6]) + (w0 ? (al)[7] : -(al)[7]) )
#define BETA_L3(al) ( (((lam >> 5) & 1) ? (al)[2] : -(al)[2]) + (((lam >> 4) & 1) ? (al)[3] : -(al)[3]) \
                    + (w1 ? (al)[4] : -(al)[4]) + (w0 ? (al)[5] : -(al)[5]) \
                    + (((lam >> 3) & 1) ? (al)[8] : -(al)[8]) + (((lam >> 2) & 1) ? (al)[9] : -(al)[9]) \
                    + (((lam >> 1) & 1) ? (al)[10] : -(al)[10]) + (((lam >> 0) & 1) ? (al)[11] : -(al)[11]) )

    // --- init diagonal: RZ(phi_0) in L1 ---
    apply_phase(st, dreg + 0 * 32, BETA_L1(alph + 0 * NQ));

    const int col_b = ((lam >> 4) << 2) | w;
    const int row_a = (w << 6) | (lam & 0x30);
    const int col_a = lam & 0xF;

    // Packed-f16 transposes (same index algebra & barrier placement as R8/R11)
#define TA_PASS() do { \
    WFENCE(); \
    _Pragma("unroll") for (int j = 0; j < 16; ++j) buf[tix * RSTR + j] = PACKH(st[j]); \
    WFENCE(); \
    _Pragma("unroll") for (int j = 0; j < 16; ++j) st[j] = UNPACKH(buf[(row_a | j) * RSTR + col_a]); \
    } while (0)

#define TB_WRITE() { _Pragma("unroll") for (int j = 0; j < 16; ++j) buf[tix * RSTR + j] = PACKH(st[j]); }
#define TB_READ()  { _Pragma("unroll") for (int j = 0; j < 16; ++j) \
        st[j] = UNPACKH(buf[(((j & 3) << 6) | ((j >> 2) << 4) | (lam & 0xF)) * RSTR + col_b]); }

#pragma unroll 1
    for (int h = 0; h < 2; ++h) {
        // ============ forward layer l = 2h : L1 -> L2 -> L3 ============
        {
            const int gb = (2 * h) * NQ;
            RYGATE(gb + 11, 0); RYGATE(gb + 10, 1); RYGATE(gb + 9, 2); RYGATE(gb + 8, 3);
            TA_PASS();                              // wave-local (prior readers in-wave or none)
            RYGATE(gb + 5, 0); RYGATE(gb + 4, 1); RYGATE(gb + 3, 2); RYGATE(gb + 2, 3);
            WFENCE();                               // prior T_a reads were wave-local
            TB_WRITE();
            __syncthreads();
            TB_READ();
            RYGATE(gb + 7, 0); RYGATE(gb + 6, 1); RYGATE(gb + 1, 2); RYGATE(gb + 0, 3);
            // CZ sign in L3 (R8-verified)
            {
                const int l5 = (lam >> 5) & 1, l4 = (lam >> 4) & 1, l3 = (lam >> 3) & 1;
                const int par = (l5 & l4) + (l4 & w1) + (w1 & w0) + __popc(lam & (lam >> 1) & 0x7);
                const float base = (par & 1) ? -1.0f : 1.0f;
                const float fA = l5 ? -1.0f : 1.0f;
                const float fB = w0 ? -1.0f : 1.0f;
                const float fC = l3 ? -1.0f : 1.0f;
#pragma unroll
                for (int j = 0; j < 16; ++j) {
                    float s = base;
                    if (j & 4) s *= fA;
                    if (j & 2) s *= fB;
                    if (j & 1) s *= fC;
                    if ((((j & 12) == 12) ? 1 : 0) ^ (((j & 3) == 3) ? 1 : 0)) s = -s;
                    st[j] *= s;
                }
            }
            apply_phase(st, dreg + (2 * h + 1) * 32, BETA_L3(alph + (2 * h + 1) * NQ));
        }
        // ============ reverse layer l = 2h+1 : L3 -> L2 -> L1 ============
        {
            const int gb = (2 * h + 1) * NQ;
            RYGATE(gb + 7, 0); RYGATE(gb + 6, 1); RYGATE(gb + 1, 2); RYGATE(gb + 0, 3);
            __syncthreads();                        // prior T_b reads cross-wave
            TB_WRITE();
            __syncthreads();
            TB_READ();
            RYGATE(gb + 5, 0); RYGATE(gb + 4, 1); RYGATE(gb + 3, 2); RYGATE(gb + 2, 3);
            __syncthreads();                        // prior T_b reads cross-wave
            TA_PASS();
            RYGATE(gb + 11, 0); RYGATE(gb + 10, 1); RYGATE(gb + 9, 2); RYGATE(gb + 8, 3);
            if (h == 0) {
                // CZ sign in L1 (R6/R8-verified)
                {
                    const int par = __popc(lam & (lam >> 1)) + ((lam & 1) & w1) + (w1 & w0);
                    const float base = (par & 1) ? -1.0f : 1.0f;
                    const float sHi = w0 ? -base : base;
#pragma unroll
                    for (int j = 0; j < 16; ++j) {
                        float s = (j & 8) ? sHi : base;
                        if (__popc(j & (j >> 1)) & 1) s = -s;
                        st[j] *= s;
                    }
                }
                apply_phase(st, dreg + 2 * 32, BETA_L1(alph + 2 * NQ));
            }
            // h==1: trailing diagonals dropped (probs phase-invariant)
        }
    }

    // --- measurement in L1 ---
    float tot = 0.f, m8 = 0.f, m9 = 0.f, m10 = 0.f, m11 = 0.f;
#pragma unroll
    for (int j = 0; j < 16; ++j) {
        const float p = st[j].x * st[j].x + st[j].y * st[j].y;
        tot += p;
        m8  += (j & 8) ? -p : p;
        m9  += (j & 4) ? -p : p;
        m10 += (j & 2) ? -p : p;
        m11 += (j & 1) ? -p : p;
    }
    float part[NQ];
#pragma unroll
    for (int q = 0; q < 6; ++q)
        part[q] = ((lam >> (5 - q)) & 1) ? -tot : tot;
    part[6] = w1 ? -tot : tot;
    part[7] = w0 ? -tot : tot;
    part[8] = m8; part[9] = m9; part[10] = m10; part[11] = m11;

#pragma unroll
    for (int off = 32; off > 0; off >>= 1) {
#pragma unroll
        for (int q = 0; q < NQ; ++q)
            part[q] += __shfl_down(part[q], off, 64);
    }
    if (lam == 0) {
#pragma unroll
        for (int q = 0; q < NQ; ++q) red[w][q] = part[q];
    }
    __syncthreads();
    if (tix < NQ) qout[tix] = red[0][tix] + red[1][tix] + red[2][tix] + red[3][tix];
    __syncthreads();

    if (tix < NA) {
        float acc = fc_b[tix];
#pragma unroll
        for (int q = 0; q < NQ; ++q)
            acc += qout[q] * fc_w[tix * NQ + q];
        out[b * NA + tix] = acc;
    }
}

extern "C" void kernel_launch(void* const* d_in, const int* in_sizes, int n_in,
                              void* d_out, int out_size, void* d_ws, size_t ws_size,
                              hipStream_t stream) {
    const float* x   = (const float*)d_in[0];
    const float* wts = (const float*)d_in[1];
    const float* fcw = (const float*)d_in[2];
    const float* fcb = (const float*)d_in[3];
    float* tabs = (float*)d_ws;   // 272 f32 = 1088 B
    setup_kernel<<<1, 64, 0, stream>>>(wts, tabs);
    qdqn_kernel<<<BATCH, NT, 0, stream>>>(x, tabs, fcw, fcb, (float*)d_out);
}

// Round 15
// 147.200 us; speedup vs baseline: 1.0266x; 1.0266x over previous
//
#include <hip/hip_runtime.h>
#include <math.h>

#define NQ 12
#define NL 4
#define NA 6
#define BATCH 4096
#define NT 256
#define NBLK (BATCH / 2)   // 2 batch elements per block
#define RSTR 17            // f2 row stride; payload = (A,B) f16x2 pair per b64 DS op

typedef float f2 __attribute__((ext_vector_type(2)));
typedef __fp16 h2 __attribute__((ext_vector_type(2)));

// HW-verified (R3-R14) packed complex primitives; (re,im) in a VGPR pair.
#define CMUL(d, u, a)  asm("v_pk_mul_f32 %0, %1, %2 op_sel_hi:[0,1]"                 : "=v"(d) : "v"(u), "v"(a))
#define CMACR(d, u, a) asm("v_pk_fma_f32 %0, %1, %2, %0 op_sel_hi:[0,1,1]"           : "+v"(d) : "v"(u), "v"(a))
#define CMACI(d, u, a) asm("v_pk_fma_f32 %0, %1, %2, %0 op_sel:[1,1,0] op_sel_hi:[1,0,1] neg_lo:[1,0,0]" : "+v"(d) : "v"(u), "v"(a))
#define RYMULS(d, u, a)  asm("v_pk_mul_f32 %0, %1, %2 op_sel:[1,0] op_sel_hi:[1,1]"  : "=v"(d) : "v"(u), "v"(a))
#define RYMACNS(d, u, a) asm("v_pk_fma_f32 %0, %1, %2, %0 op_sel:[1,0,0] op_sel_hi:[1,1,1] neg_lo:[1,0,0] neg_hi:[1,0,0]" : "+v"(d) : "v"(u), "v"(a))
#define WFENCE() asm volatile("s_waitcnt lgkmcnt(0)" ::: "memory")

// f2 <-> packed f16x2 in one f32 slot (R14-verified)
#define PACKH(v)   ({ union { h2 h; float f; } _u; _u.h = __builtin_amdgcn_cvt_pkrtz((v).x, (v).y); _u.f; })
#define UNPACKH(fv) ({ union { h2 h; float f; } _u; _u.f = (fv); (f2){ (float)_u.h.x, (float)_u.h.y }; })
#define PACK2(a, b) ((f2){ PACKH(a), PACKH(b) })

// Real RY butterfly: n0 = c*a0 - s*a1 ; n1 = s*a0 + c*a1   (4 pk ops; R10-verified)
#define RYBFLY(A0, A1, CS) do { \
    f2 _a0 = (A0), _a1 = (A1), _n0, _n1; \
    CMUL  (_n0, CS, _a0); RYMACNS(_n0, CS, _a1); \
    RYMULS(_n1, CS, _a0); CMACR  (_n1, CS, _a1); \
    (A0) = _n0; (A1) = _n1; } while (0)

// Gate on both batch elements; coefficient load + loop overhead shared (R12-verified).
#define RYGATE2(gidx, bq) do { \
    const f2 cs = *(const f2*)(rots + (gidx) * 2); \
    const int S = 1 << (bq); \
    _Pragma("unroll") \
    for (int m = 0; m < 8; ++m) { \
        const int j0 = ((m & ~(S - 1)) << 1) | (m & (S - 1)); \
        RYBFLY(stA[j0], stA[j0 + S], cs); \
        RYBFLY(stB[j0], stB[j0 + S], cs); \
    } } while (0)

// Circuit algebra (R10), layouts/transposes/CZ parities (R8/R11/R14): all HW-verified, verbatim.
// R15: 2 batch elements/block; transpose payload = both elements' f16x2 in one b64 ->
// per-element DS insts and barrier events halve; zero serialization (unlike R12).
// d_ws: [0..95] 48 gates (c,s) | [96..143] alphas[4][12] | [144..271] dreg[4][16] (re,im)

__global__ void setup_kernel(const float* __restrict__ weights, float* __restrict__ ws) {
    const int t = threadIdx.x;   // 64 threads
    if (t < NL * NQ) {
        const float th = weights[t * 3 + 1];
        float s, c;
        sincosf(0.5f * th, &s, &c);
        ws[t * 2 + 0] = c; ws[t * 2 + 1] = s;
        const int r = t / NQ, q = t % NQ;
        float a;
        if (r == 0) a = 0.5f * weights[q * 3 + 0];
        else        a = 0.5f * (weights[((r - 1) * NQ + q) * 3 + 2] +
                                 weights[(r * NQ + q) * 3 + 0]);
        ws[96 + t] = a;
    }
    {
        const int d = t >> 4, j = t & 15;
        int wq[4];
        if (d == 1 || d == 3) { wq[0] = 0; wq[1] = 1; wq[2] = 6; wq[3] = 7; }
        else                  { wq[0] = 8; wq[1] = 9; wq[2] = 10; wq[3] = 11; }
        float g = 0.0f;
#pragma unroll
        for (int k = 0; k < 4; ++k) {
            const int q = wq[k];
            const float a = (d == 0) ? 0.5f * weights[q * 3 + 0]
                                     : 0.5f * (weights[((d - 1) * NQ + q) * 3 + 2] +
                                               weights[(d * NQ + q) * 3 + 0]);
            g += ((j >> (3 - k)) & 1) ? a : -a;
        }
        float sg, cg;
        sincosf(g, &sg, &cg);
        ws[144 + (d * 16 + j) * 2 + 0] = cg;
        ws[144 + (d * 16 + j) * 2 + 1] = sg;
    }
}

__global__ __launch_bounds__(NT) void qdqn_kernel(
    const float* __restrict__ x,       // [BATCH,12]
    const float* __restrict__ rots,    // d_ws tables
    const float* __restrict__ fc_w,    // [6,12]
    const float* __restrict__ fc_b,    // [6]
    float* __restrict__ out)           // [BATCH,6]
{
    __shared__ __align__(16) f2 buf[NT * RSTR];   // 34816 B; .x = elem A packed, .y = elem B packed
    __shared__ float encc[2][NQ], encs[2][NQ];
    __shared__ float redA[4][NQ], redB[4][NQ];
    __shared__ float qoutA[NQ], qoutB[NQ];

    const int tix = threadIdx.x;
    const int lam = tix & 63;
    const int w   = tix >> 6;
    const int w1  = (w >> 1) & 1, w0 = w & 1;
    const int b0  = blockIdx.x * 2;

    const float* alph = rots + 96;
    const float* dreg = rots + 144;

    if (tix < 2 * NQ) {
        const int s = tix / NQ, q = tix % NQ;
        float sn, cs;
        sincosf(0.5f * x[(b0 + s) * NQ + q], &sn, &cs);
        encc[s][q] = cs; encs[s][q] = sn;
    }
    __syncthreads();

    // --- RY product states in L1 (real) ---
    f2 stA[16], stB[16];
#pragma unroll
    for (int s = 0; s < 2; ++s) {
        const float* ec = encc[s];
        const float* es = encs[s];
        float pre = 1.0f;
#pragma unroll
        for (int q = 0; q < 6; ++q)
            pre *= ((lam >> (5 - q)) & 1) ? es[q] : ec[q];
        pre *= w1 ? es[6] : ec[6];
        pre *= w0 ? es[7] : ec[7];
        const float c8 = ec[8],  s8 = es[8];
        const float c9 = ec[9],  s9 = es[9];
        const float cA = ec[10], sA = es[10];
        const float cB = ec[11], sB = es[11];
        f2* st = s ? stB : stA;
#pragma unroll
        for (int j = 0; j < 16; ++j) {
            float v = pre;
            v *= (j & 8) ? s8 : c8;
            v *= (j & 4) ? s9 : c9;
            v *= (j & 2) ? sA : cA;
            v *= (j & 1) ? sB : cB;
            st[j] = (f2){ v, 0.0f };
        }
    }

#define BETA_L1(al) ( (((lam >> 5) & 1) ? (al)[0] : -(al)[0]) + (((lam >> 4) & 1) ? (al)[1] : -(al)[1]) \
                    + (((lam >> 3) & 1) ? (al)[2] : -(al)[2]) + (((lam >> 2) & 1) ? (al)[3] : -(al)[3]) \
                    + (((lam >> 1) & 1) ? (al)[4] : -(al)[4]) + (((lam >> 0) & 1) ? (al)[5] : -(al)[5]) \
                    + (w1 ? (al)[6] : -(al)[6]) + (w0 ? (al)[7] : -(al)[7]) )
#define BETA_L3(al) ( (((lam >> 5) & 1) ? (al)[2] : -(al)[2]) + (((lam >> 4) & 1) ? (al)[3] : -(al)[3]) \
                    + (w1 ? (al)[4] : -(al)[4]) + (w0 ? (al)[5] : -(al)[5]) \
                    + (((lam >> 3) & 1) ? (al)[8] : -(al)[8]) + (((lam >> 2) & 1) ? (al)[9] : -(al)[9]) \
                    + (((lam >> 1) & 1) ? (al)[10] : -(al)[10]) + (((lam >> 0) & 1) ? (al)[11] : -(al)[11]) )

    // Phase on both states; sincos/beta/dg-load shared (R12-verified).
#define APPLY_PHASE2(tab, beta) do { \
    float _sb, _cb; \
    sincosf((beta), &_sb, &_cb); \
    const f2 _Dth = (f2){_cb, _sb}; \
    _Pragma("unroll") \
    for (int j = 0; j < 16; ++j) { \
        const f2 _dg = *(const f2*)((tab) + 2 * j); \
        f2 _t, _u; \
        CMUL(_t, _Dth, stA[j]); CMACI(_t, _Dth, stA[j]); \
        CMUL(_u, _dg, _t);      CMACI(_u, _dg, _t); \
        stA[j] = _u; \
        CMUL(_t, _Dth, stB[j]); CMACI(_t, _Dth, stB[j]); \
        CMUL(_u, _dg, _t);      CMACI(_u, _dg, _t); \
        stB[j] = _u; \
    } } while (0)

    // --- init diagonal: RZ(phi_0) in L1 ---
    APPLY_PHASE2(dreg + 0 * 32, BETA_L1(alph + 0 * NQ));

    const int col_b = ((lam >> 4) << 2) | w;
    const int row_a = (w << 6) | (lam & 0x30);
    const int col_a = lam & 0xF;

    // Dual-payload transposes: same index algebra & barrier placement as R8/R11/R14.
#define TA_PASS() do { \
    WFENCE(); \
    _Pragma("unroll") for (int j = 0; j < 16; ++j) buf[tix * RSTR + j] = PACK2(stA[j], stB[j]); \
    WFENCE(); \
    _Pragma("unroll") for (int j = 0; j < 16; ++j) { \
        const f2 _v = buf[(row_a | j) * RSTR + col_a]; \
        stA[j] = UNPACKH(_v.x); stB[j] = UNPACKH(_v.y); } \
    } while (0)

#define TB_WRITE() { _Pragma("unroll") for (int j = 0; j < 16; ++j) buf[tix * RSTR + j] = PACK2(stA[j], stB[j]); }
#define TB_READ()  { _Pragma("unroll") for (int j = 0; j < 16; ++j) { \
        const f2 _v = buf[(((j & 3) << 6) | ((j >> 2) << 4) | (lam & 0xF)) * RSTR + col_b]; \
        stA[j] = UNPACKH(_v.x); stB[j] = UNPACKH(_v.y); } }

#pragma unroll 1
    for (int h = 0; h < 2; ++h) {
        // ============ forward layer l = 2h : L1 -> L2 -> L3 ============
        {
            const int gb = (2 * h) * NQ;
            RYGATE2(gb + 11, 0); RYGATE2(gb + 10, 1); RYGATE2(gb + 9, 2); RYGATE2(gb + 8, 3);
            TA_PASS();                              // wave-local
            RYGATE2(gb + 5, 0); RYGATE2(gb + 4, 1); RYGATE2(gb + 3, 2); RYGATE2(gb + 2, 3);
            WFENCE();                               // prior T_a reads were wave-local
            TB_WRITE();
            __syncthreads();
            TB_READ();
            RYGATE2(gb + 7, 0); RYGATE2(gb + 6, 1); RYGATE2(gb + 1, 2); RYGATE2(gb + 0, 3);
            // CZ sign in L3 (R8-verified), once, both states
            {
                const int l5 = (lam >> 5) & 1, l4 = (lam >> 4) & 1, l3 = (lam >> 3) & 1;
                const int par = (l5 & l4) + (l4 & w1) + (w1 & w0) + __popc(lam & (lam >> 1) & 0x7);
                const float base = (par & 1) ? -1.0f : 1.0f;
                const float fA = l5 ? -1.0f : 1.0f;
                const float fB = w0 ? -1.0f : 1.0f;
                const float fC = l3 ? -1.0f : 1.0f;
#pragma unroll
                for (int j = 0; j < 16; ++j) {
                    float s = base;
                    if (j & 4) s *= fA;
                    if (j & 2) s *= fB;
                    if (j & 1) s *= fC;
                    if ((((j & 12) == 12) ? 1 : 0) ^ (((j & 3) == 3) ? 1 : 0)) s = -s;
                    stA[j] *= s;
                    stB[j] *= s;
                }
            }
            APPLY_PHASE2(dreg + (2 * h + 1) * 32, BETA_L3(alph + (2 * h + 1) * NQ));
        }
        // ============ reverse layer l = 2h+1 : L3 -> L2 -> L1 ============
        {
            const int gb = (2 * h + 1) * NQ;
            RYGATE2(gb + 7, 0); RYGATE2(gb + 6, 1); RYGATE2(gb + 1, 2); RYGATE2(gb + 0, 3);
            __syncthreads();                        // prior T_b reads cross-wave
            TB_WRITE();
            __syncthreads();
            TB_READ();
            RYGATE2(gb + 5, 0); RYGATE2(gb + 4, 1); RYGATE2(gb + 3, 2); RYGATE2(gb + 2, 3);
            __syncthreads();                        // prior T_b reads cross-wave
            TA_PASS();
            RYGATE2(gb + 11, 0); RYGATE2(gb + 10, 1); RYGATE2(gb + 9, 2); RYGATE2(gb + 8, 3);
            if (h == 0) {
                // CZ sign in L1 (R6/R8-verified), once, both states
                {
                    const int par = __popc(lam & (lam >> 1)) + ((lam & 1) & w1) + (w1 & w0);
                    const float base = (par & 1) ? -1.0f : 1.0f;
                    const float sHi = w0 ? -base : base;
#pragma unroll
                    for (int j = 0; j < 16; ++j) {
                        float s = (j & 8) ? sHi : base;
                        if (__popc(j & (j >> 1)) & 1) s = -s;
                        stA[j] *= s;
                        stB[j] *= s;
                    }
                }
                APPLY_PHASE2(dreg + 2 * 32, BETA_L1(alph + 2 * NQ));
            }
            // h==1: trailing diagonals dropped (probs phase-invariant)
        }
    }

    // --- measurement in L1, both states (R12-verified tail) ---
    float totA = 0.f, a8 = 0.f, a9 = 0.f, a10 = 0.f, a11 = 0.f;
    float totB = 0.f, b8 = 0.f, b9 = 0.f, b10 = 0.f, b11 = 0.f;
#pragma unroll
    for (int j = 0; j < 16; ++j) {
        const float pA = stA[j].x * stA[j].x + stA[j].y * stA[j].y;
        const float pB = stB[j].x * stB[j].x + stB[j].y * stB[j].y;
        totA += pA; totB += pB;
        a8  += (j & 8) ? -pA : pA;  b8  += (j & 8) ? -pB : pB;
        a9  += (j & 4) ? -pA : pA;  b9  += (j & 4) ? -pB : pB;
        a10 += (j & 2) ? -pA : pA;  b10 += (j & 2) ? -pB : pB;
        a11 += (j & 1) ? -pA : pA;  b11 += (j & 1) ? -pB : pB;
    }
    float pA[NQ], pB[NQ];
#pragma unroll
    for (int q = 0; q < 6; ++q) {
        const int bit = (lam >> (5 - q)) & 1;
        pA[q] = bit ? -totA : totA;
        pB[q] = bit ? -totB : totB;
    }
    pA[6] = w1 ? -totA : totA;  pB[6] = w1 ? -totB : totB;
    pA[7] = w0 ? -totA : totA;  pB[7] = w0 ? -totB : totB;
    pA[8] = a8; pA[9] = a9; pA[10] = a10; pA[11] = a11;
    pB[8] = b8; pB[9] = b9; pB[10] = b10; pB[11] = b11;

#pragma unroll
    for (int off = 32; off > 0; off >>= 1) {
#pragma unroll
        for (int q = 0; q < NQ; ++q) {
            pA[q] += __shfl_down(pA[q], off, 64);
            pB[q] += __shfl_down(pB[q], off, 64);
        }
    }
    if (lam == 0) {
#pragma unroll
        for (int q = 0; q < NQ; ++q) { redA[w][q] = pA[q]; redB[w][q] = pB[q]; }
    }
    __syncthreads();
    if (tix < NQ) {
        qoutA[tix] = redA[0][tix] + redA[1][tix] + redA[2][tix] + redA[3][tix];
        qoutB[tix] = redB[0][tix] + redB[1][tix] + redB[2][tix] + redB[3][tix];
    }
    __syncthreads();

    if (tix < NA) {
        float accA = fc_b[tix], accB = accA;
#pragma unroll
        for (int q = 0; q < NQ; ++q) {
            const float f = fc_w[tix * NQ + q];
            accA += qoutA[q] * f;
            accB += qoutB[q] * f;
        }
        out[b0 * NA + tix] = accA;
        out[(b0 + 1) * NA + tix] = accB;
    }
}

extern "C" void kernel_launch(void* const* d_in, const int* in_sizes, int n_in,
                              void* d_out, int out_size, void* d_ws, size_t ws_size,
                              hipStream_t stream) {
    const float* x   = (const float*)d_in[0];
    const float* wts = (const float*)d_in[1];
    const float* fcw = (const float*)d_in[2];
    const float* fcb = (const float*)d_in[3];
    float* tabs = (float*)d_ws;   // 272 f32 = 1088 B
    setup_kernel<<<1, 64, 0, stream>>>(wts, tabs);
    qdqn_kernel<<<NBLK, NT, 0, stream>>>(x, tabs, fcw, fcb, (float*)d_out);
}